// Round 4
// baseline (178.482 us; speedup 1.0000x reference)
//
#include <hip/hip_runtime.h>
#include <math.h>

#define DD 32
#define HH 128

// ws layout (floats):
//   [0, 4096)        w1t   : w1t[k*32+j] = vW1[j][k]        (16 KB)
//   [4096, 4224)     c0    : vb1[k] + t * vW1[32][k]        (512 B)
//   [4224, 8320)     pw1t  : pw1t[k*32+j] = pW1[j][k]       (16 KB)
//   [8320, 8512)     tripg : 6 x 32 raw triple gradients    (768 B)
#define WS_W1T   0
#define WS_C0    4096
#define WS_PW1T  4224
#define WS_TRIPG 8320

// fast tanh: tanh(x) = sign(x) * (1 - e^{-2|x|}) / (1 + e^{-2|x|})
__device__ __forceinline__ float fast_tanh(float x) {
    float ax = fabsf(x);
    float e  = __expf(-2.0f * ax);
    float r  = __fdividef(1.0f - e, 1.0f + e);
    return copysignf(r, x);
}

// -------- Prep: transpose weights into ws, fold bias+t ---------------------
__global__ void k_prep(const float* __restrict__ t,
                       const float* __restrict__ vW1,  // (33,128)
                       const float* __restrict__ vb1,
                       const float* __restrict__ pW1,  // (32,128)
                       float* __restrict__ ws)
{
    int i = blockIdx.x * 256 + threadIdx.x;
    if (i < HH * DD) {
        int k = i / DD, j = i % DD;
        ws[WS_W1T  + i] = vW1[j * HH + k];
        ws[WS_PW1T + i] = pW1[j * HH + k];
        if (j == 0) ws[WS_C0 + k] = vb1[k] + t[0] * vW1[DD * HH + k];
    }
}

// -------- Kernel 1: dz_dt = tanh([z, t] @ vW1 + vb1) @ vW2 + vb2 ----------
// One thread per row. Weights read with thread-UNIFORM addresses from
// const __restrict__ global memory -> compiler emits s_load into SGPRs;
// FMAs use the SGPR operand slot. No LDS at all.
__global__ __launch_bounds__(256) void k_dzdt(
    const float* __restrict__ z,
    const float* __restrict__ w1t,   // ws + WS_W1T  (128 x 32)
    const float* __restrict__ c0,    // ws + WS_C0   (128)
    const float* __restrict__ vW2,   // (128,32) row-major
    const float* __restrict__ vb2,   // (32)
    float* __restrict__ out,
    int B)
{
    int row = blockIdx.x * 256 + threadIdx.x;
    if (row >= B) return;

    float zr[DD];
    {
        const float4* zp = (const float4*)(z + (size_t)row * DD);
        #pragma unroll
        for (int q = 0; q < 8; q++) {
            float4 v = zp[q];
            zr[4*q+0] = v.x; zr[4*q+1] = v.y; zr[4*q+2] = v.z; zr[4*q+3] = v.w;
        }
    }

    float acc[DD];
    {
        const float4* b4 = (const float4*)vb2;
        #pragma unroll
        for (int q = 0; q < 8; q++) {
            float4 b = b4[q];
            acc[4*q+0] = b.x; acc[4*q+1] = b.y; acc[4*q+2] = b.z; acc[4*q+3] = b.w;
        }
    }

    #pragma unroll 2
    for (int k = 0; k < HH; k++) {
        const float4* c4 = (const float4*)(w1t + k * DD);   // uniform -> s_load
        float u0 = c0[k], u1 = 0.f, u2 = 0.f, u3 = 0.f;
        #pragma unroll
        for (int q = 0; q < 8; q++) {
            float4 c = c4[q];
            u0 = fmaf(zr[4*q+0], c.x, u0);
            u1 = fmaf(zr[4*q+1], c.y, u1);
            u2 = fmaf(zr[4*q+2], c.z, u2);
            u3 = fmaf(zr[4*q+3], c.w, u3);
        }
        float hk = fast_tanh((u0 + u1) + (u2 + u3));

        const float4* w4 = (const float4*)(vW2 + k * DD);   // uniform -> s_load
        #pragma unroll
        for (int q = 0; q < 8; q++) {
            float4 w = w4[q];
            acc[4*q+0] = fmaf(hk, w.x, acc[4*q+0]);
            acc[4*q+1] = fmaf(hk, w.y, acc[4*q+1]);
            acc[4*q+2] = fmaf(hk, w.z, acc[4*q+2]);
            acc[4*q+3] = fmaf(hk, w.w, acc[4*q+3]);
        }
    }

    float4* op = (float4*)(out + (size_t)row * DD);
    #pragma unroll
    for (int q = 0; q < 8; q++)
        op[q] = make_float4(acc[4*q+0], acc[4*q+1], acc[4*q+2], acc[4*q+3]);
}

// -------- Kernel 2: pair forces (and 6 off-diagonal triple grads) ----------
// g_j(d) = sum_k pW1[j][k] * pW2[k] * (1 - tanh^2(d@pW1 + pb1)_k)
// perm is a permutation -> pair rows disjoint -> plain RMW on out, no atomics.
__global__ __launch_bounds__(256) void k_force(
    const float* __restrict__ z,
    const int*   __restrict__ perm,
    const float* __restrict__ pw1t,  // ws + WS_PW1T (128 x 32)
    const float* __restrict__ pb1,   // (128)
    const float* __restrict__ pW2,   // (128)
    float* __restrict__ out,
    float* __restrict__ tripg,       // ws + WS_TRIPG
    int num_pairs, int nwork)
{
    int p = blockIdx.x * 256 + threadIdx.x;
    if (p >= nwork) return;

    bool is_triple = (p >= num_pairs);
    int tidx = 0, ia, ib;
    if (!is_triple) {
        ia = perm[2 * p];
        ib = perm[2 * p + 1];
    } else {
        tidx = p - num_pairs;            // 0..5 enumerates (i,j), j != i
        int i = tidx >> 1, r = tidx & 1;
        int j = r + ((r >= i) ? 1 : 0);
        ia = perm[2 * num_pairs + i];
        ib = perm[2 * num_pairs + j];
    }

    float diff[DD];
    {
        const float4* za = (const float4*)(z + (size_t)ia * DD);
        const float4* zb = (const float4*)(z + (size_t)ib * DD);
        #pragma unroll
        for (int q = 0; q < 8; q++) {
            float4 A = za[q], Bv = zb[q];
            diff[4*q+0] = A.x - Bv.x;
            diff[4*q+1] = A.y - Bv.y;
            diff[4*q+2] = A.z - Bv.z;
            diff[4*q+3] = A.w - Bv.w;
        }
    }

    float g[DD];
    #pragma unroll
    for (int j = 0; j < DD; j++) g[j] = 0.f;

    #pragma unroll 2
    for (int k = 0; k < HH; k++) {
        const float4* c4 = (const float4*)(pw1t + k * DD);  // uniform -> s_load
        float4 c0_ = c4[0], c1_ = c4[1], c2_ = c4[2], c3_ = c4[3];
        float4 c4_ = c4[4], c5_ = c4[5], c6_ = c4[6], c7_ = c4[7];

        float u0 = pb1[k], u1 = 0.f, u2 = 0.f, u3 = 0.f;
        u0 = fmaf(diff[ 0], c0_.x, u0); u1 = fmaf(diff[ 1], c0_.y, u1);
        u2 = fmaf(diff[ 2], c0_.z, u2); u3 = fmaf(diff[ 3], c0_.w, u3);
        u0 = fmaf(diff[ 4], c1_.x, u0); u1 = fmaf(diff[ 5], c1_.y, u1);
        u2 = fmaf(diff[ 6], c1_.z, u2); u3 = fmaf(diff[ 7], c1_.w, u3);
        u0 = fmaf(diff[ 8], c2_.x, u0); u1 = fmaf(diff[ 9], c2_.y, u1);
        u2 = fmaf(diff[10], c2_.z, u2); u3 = fmaf(diff[11], c2_.w, u3);
        u0 = fmaf(diff[12], c3_.x, u0); u1 = fmaf(diff[13], c3_.y, u1);
        u2 = fmaf(diff[14], c3_.z, u2); u3 = fmaf(diff[15], c3_.w, u3);
        u0 = fmaf(diff[16], c4_.x, u0); u1 = fmaf(diff[17], c4_.y, u1);
        u2 = fmaf(diff[18], c4_.z, u2); u3 = fmaf(diff[19], c4_.w, u3);
        u0 = fmaf(diff[20], c5_.x, u0); u1 = fmaf(diff[21], c5_.y, u1);
        u2 = fmaf(diff[22], c5_.z, u2); u3 = fmaf(diff[23], c5_.w, u3);
        u0 = fmaf(diff[24], c6_.x, u0); u1 = fmaf(diff[25], c6_.y, u1);
        u2 = fmaf(diff[26], c6_.z, u2); u3 = fmaf(diff[27], c6_.w, u3);
        u0 = fmaf(diff[28], c7_.x, u0); u1 = fmaf(diff[29], c7_.y, u1);
        u2 = fmaf(diff[30], c7_.z, u2); u3 = fmaf(diff[31], c7_.w, u3);

        float th = fast_tanh((u0 + u1) + (u2 + u3));
        float w  = pW2[k] * (1.0f - th * th);

        g[ 0] = fmaf(w, c0_.x, g[ 0]); g[ 1] = fmaf(w, c0_.y, g[ 1]);
        g[ 2] = fmaf(w, c0_.z, g[ 2]); g[ 3] = fmaf(w, c0_.w, g[ 3]);
        g[ 4] = fmaf(w, c1_.x, g[ 4]); g[ 5] = fmaf(w, c1_.y, g[ 5]);
        g[ 6] = fmaf(w, c1_.z, g[ 6]); g[ 7] = fmaf(w, c1_.w, g[ 7]);
        g[ 8] = fmaf(w, c2_.x, g[ 8]); g[ 9] = fmaf(w, c2_.y, g[ 9]);
        g[10] = fmaf(w, c2_.z, g[10]); g[11] = fmaf(w, c2_.w, g[11]);
        g[12] = fmaf(w, c3_.x, g[12]); g[13] = fmaf(w, c3_.y, g[13]);
        g[14] = fmaf(w, c3_.z, g[14]); g[15] = fmaf(w, c3_.w, g[15]);
        g[16] = fmaf(w, c4_.x, g[16]); g[17] = fmaf(w, c4_.y, g[17]);
        g[18] = fmaf(w, c4_.z, g[18]); g[19] = fmaf(w, c4_.w, g[19]);
        g[20] = fmaf(w, c5_.x, g[20]); g[21] = fmaf(w, c5_.y, g[21]);
        g[22] = fmaf(w, c5_.z, g[22]); g[23] = fmaf(w, c5_.w, g[23]);
        g[24] = fmaf(w, c6_.x, g[24]); g[25] = fmaf(w, c6_.y, g[25]);
        g[26] = fmaf(w, c6_.z, g[26]); g[27] = fmaf(w, c6_.w, g[27]);
        g[28] = fmaf(w, c7_.x, g[28]); g[29] = fmaf(w, c7_.y, g[29]);
        g[30] = fmaf(w, c7_.z, g[30]); g[31] = fmaf(w, c7_.w, g[31]);
    }

    if (!is_triple) {
        float4* oa = (float4*)(out + (size_t)ia * DD);
        float4* ob = (float4*)(out + (size_t)ib * DD);
        #pragma unroll
        for (int q = 0; q < 8; q++) {
            float4 va = oa[q], vb = ob[q];
            va.x -= g[4*q+0]; va.y -= g[4*q+1]; va.z -= g[4*q+2]; va.w -= g[4*q+3];
            vb.x += g[4*q+0]; vb.y += g[4*q+1]; vb.z += g[4*q+2]; vb.w += g[4*q+3];
            oa[q] = va; ob[q] = vb;
        }
    } else {
        float4* wp = (float4*)(tripg + (size_t)tidx * DD);
        #pragma unroll
        for (int q = 0; q < 8; q++)
            wp[q] = make_float4(g[4*q+0], g[4*q+1], g[4*q+2], g[4*q+3]);
    }
}

// -------- Kernel 3: deterministic triple combine ---------------------------
__global__ void k_triple_combine(
    const int*   __restrict__ perm,
    const float* __restrict__ tripg,
    float* __restrict__ out,
    int num_pairs)
{
    int tid = threadIdx.x;
    if (tid >= 3 * DD) return;
    int i = tid >> 5, d = tid & (DD - 1);
    int row = perm[2 * num_pairs + i];
    float s = tripg[(size_t)(2 * i) * DD + d] + tripg[(size_t)(2 * i + 1) * DD + d];
    out[(size_t)row * DD + d] -= 2.0f * s;
}

extern "C" void kernel_launch(void* const* d_in, const int* in_sizes, int n_in,
                              void* d_out, int out_size, void* d_ws, size_t ws_size,
                              hipStream_t stream) {
    const float* t    = (const float*)d_in[0];
    const float* z    = (const float*)d_in[1];
    const int*   perm = (const int*)  d_in[2];
    const float* vW1  = (const float*)d_in[3];
    const float* vb1  = (const float*)d_in[4];
    const float* vW2  = (const float*)d_in[5];
    // d_in[6] = vb2 below; d_in[10] = pb2: constant, vanishes under grad.
    const float* vb2  = (const float*)d_in[6];
    const float* pW1  = (const float*)d_in[7];
    const float* pb1  = (const float*)d_in[8];
    const float* pW2  = (const float*)d_in[9];

    float* out = (float*)d_out;
    float* ws  = (float*)d_ws;

    int B = in_sizes[2];                 // perm length == batch size
    int num_pairs, num_triples;
    if ((B & 1) == 0) { num_pairs = B / 2;       num_triples = 0; }
    else              { num_pairs = (B - 3) / 2; num_triples = 1; }

    k_prep<<<(HH * DD + 255) / 256, 256, 0, stream>>>(t, vW1, vb1, pW1, ws);

    int grid1 = (B + 255) / 256;
    k_dzdt<<<grid1, 256, 0, stream>>>(z, ws + WS_W1T, ws + WS_C0, vW2, vb2,
                                      out, B);

    int nwork = num_pairs + (num_triples ? 6 : 0);
    if (nwork > 0) {
        int grid2 = (nwork + 255) / 256;
        k_force<<<grid2, 256, 0, stream>>>(z, perm, ws + WS_PW1T, pb1, pW2,
                                           out, ws + WS_TRIPG,
                                           num_pairs, nwork);
    }
    if (num_triples) {
        k_triple_combine<<<1, 128, 0, stream>>>(perm, ws + WS_TRIPG, out,
                                                num_pairs);
    }
}

// Round 6
// 92.419 us; speedup vs baseline: 1.9312x; 1.9312x over previous
//
#include <hip/hip_runtime.h>
#include <math.h>

#define DD 32
#define HH 128

typedef __attribute__((ext_vector_type(8))) __bf16 bf16x8;
typedef __attribute__((ext_vector_type(4))) float  f32x4;
typedef __attribute__((ext_vector_type(2))) int    i32x2;

// ---- ws layout (float offsets) -------------------------------------------
// [0,128)        c0    : vb1[kh] + t * vW1[32][kh]
// [128,320)      tripg : 6 x 32 raw triple gradients
// [320,16704)    frags : 64 MFMA weight fragments, each 64 lanes x 16B
#define WS_C0    0
#define WS_TRIPG 128
#define WS_FRAG  320
// fragment class bases (frag index)
#define FW1H 0
#define FW1L 8
#define FW2H 16
#define FW2L 24
#define FP1H 32
#define FP1L 40
#define FPTH 48
#define FPTL 56

__device__ __forceinline__ f32x4 mfma16(bf16x8 a, bf16x8 b, f32x4 c) {
    return __builtin_amdgcn_mfma_f32_16x16x32_bf16(a, b, c, 0, 0, 0);
}

// fast tanh: tanh(x) = sign(x) * (1 - e^{-2|x|}) / (1 + e^{-2|x|})
__device__ __forceinline__ float fast_tanh(float x) {
    float ax = fabsf(x);
    float e  = __expf(-2.0f * ax);
    float r  = __fdividef(1.0f - e, 1.0f + e);
    return copysignf(r, x);
}

// sech^2(x) = 4 e^{-2|x|} / (1 + e^{-2|x|})^2   (== 1 - tanh^2)
__device__ __forceinline__ float sech2(float x) {
    float ax  = fabsf(x);
    float e   = __expf(-2.0f * ax);
    float inv = __fdividef(1.0f, 1.0f + e);
    return 4.0f * e * inv * inv;
}

// ---- Prep: build c0 and all weight MFMA fragments in ws -------------------
// Fragment conventions (16x16x32 bf16 MFMA, lane l: g=l>>4, m=l&15):
//   A-operand: row = m, k-slot i -> k = kappa(g,i)
//   B-operand: col = m, k-slot i -> k = kappa(g,i)
//   GEMM1 (K=32):  kappa1(g,i) = 8g + i
//   GEMM2 (K=128, step s): kappa2(g,s,i) = 16*(2s + (i>>2)) + 4g + (i&3)
// Correct for ANY true hw k-ordering as long as A and B share kappa.
__global__ void k_prep(const float* __restrict__ t,
                       const float* __restrict__ vW1,  // (33,128)
                       const float* __restrict__ vb1,  // (128)
                       const float* __restrict__ vW2,  // (128,32)
                       const float* __restrict__ pW1,  // (32,128)
                       float* __restrict__ ws)
{
    int tid = blockIdx.x * 256 + threadIdx.x;
    if (tid < 4096) {
        int f = tid >> 6, l = tid & 63;
        int g = l >> 4, m = l & 15;
        int cls = f >> 4;          // 0:W1-A  1:W2-B  2:P1-A  3:PT-B
        int q = f & 15;
        bool isLo = (q >= 8);
        int idx = q & 7;
        float v[8];
        if (cls == 0 || cls == 2) {
            const float* W = (cls == 0) ? vW1 : pW1;
            int th = idx;          // A value = W^T[kh][j] = W[j][kh], kh=16th+m, j=8g+i
            #pragma unroll
            for (int i = 0; i < 8; i++)
                v[i] = W[(8 * g + i) * HH + 16 * th + m];
        } else {
            int nt = idx >> 2, s = idx & 3;
            #pragma unroll
            for (int i = 0; i < 8; i++) {
                int kh = 16 * (2 * s + (i >> 2)) + 4 * g + (i & 3);
                v[i] = (cls == 1) ? vW2[kh * DD + nt * 16 + m]       // B=W2[kh][j]
                                  : pW1[(nt * 16 + m) * HH + kh];    // B=pW1^T[kh][j]
            }
        }
        bf16x8 o;
        #pragma unroll
        for (int i = 0; i < 8; i++) {
            __bf16 h = (__bf16)v[i];
            o[i] = isLo ? (__bf16)(v[i] - (float)h) : h;
        }
        *(bf16x8*)(ws + WS_FRAG + (size_t)(f * 64 + l) * 4) = o;
    } else if (tid < 4096 + HH) {
        int k = tid - 4096;
        ws[WS_C0 + k] = vb1[k] + t[0] * vW1[DD * HH + k];
    }
}

// ---- Kernel 1: dz_dt = tanh([z,t] @ vW1 + vb1) @ vW2 + vb2 ---------------
// Per wave: 16-row tiles. GEMM1 transposed (A=W1^T frags, B=z^T) so h lands
// at m=lane&15 == exactly GEMM2's A-layout row -> h never leaves the lane.
__global__ __launch_bounds__(256) void k_dzdt(
    const float* __restrict__ z,
    const float* __restrict__ ws,
    const float* __restrict__ vb2,
    float* __restrict__ out,
    int B)
{
    int lane = threadIdx.x & 63;
    int wid  = blockIdx.x * (blockDim.x >> 6) + (threadIdx.x >> 6);
    int nw   = gridDim.x * (blockDim.x >> 6);
    int g = lane >> 4, m = lane & 15;

    bf16x8 w1h[8], w1l[8], w2h[8], w2l[8];
    #pragma unroll
    for (int q = 0; q < 8; q++) {
        w1h[q] = *(const bf16x8*)(ws + WS_FRAG + (size_t)((FW1H + q) * 64 + lane) * 4);
        w1l[q] = *(const bf16x8*)(ws + WS_FRAG + (size_t)((FW1L + q) * 64 + lane) * 4);
        w2h[q] = *(const bf16x8*)(ws + WS_FRAG + (size_t)((FW2H + q) * 64 + lane) * 4);
        w2l[q] = *(const bf16x8*)(ws + WS_FRAG + (size_t)((FW2L + q) * 64 + lane) * 4);
    }
    f32x4 c0f[8];
    #pragma unroll
    for (int th = 0; th < 8; th++)
        c0f[th] = *(const f32x4*)(ws + WS_C0 + 16 * th + 4 * g);
    float vb2v[2];
    vb2v[0] = vb2[m]; vb2v[1] = vb2[16 + m];

    int ntiles = (B + 15) >> 4;
    for (int tt = wid; tt < ntiles; tt += nw) {
        int rbase = tt * 16;
        int zrow = rbase + m; if (zrow >= B) zrow = 0;
        f32x4 za = *(const f32x4*)(z + (size_t)zrow * DD + 8 * g);
        f32x4 zb = *(const f32x4*)(z + (size_t)zrow * DD + 8 * g + 4);
        bf16x8 zh, zl;
        #pragma unroll
        for (int i = 0; i < 4; i++) {
            __bf16 h = (__bf16)za[i]; zh[i] = h; zl[i] = (__bf16)(za[i] - (float)h);
        }
        #pragma unroll
        for (int i = 0; i < 4; i++) {
            __bf16 h = (__bf16)zb[i]; zh[4 + i] = h; zl[4 + i] = (__bf16)(zb[i] - (float)h);
        }

        f32x4 acc1[8];
        #pragma unroll
        for (int th = 0; th < 8; th++) {
            f32x4 a = c0f[th];
            a = mfma16(w1h[th], zl, a);
            a = mfma16(w1l[th], zh, a);
            a = mfma16(w1h[th], zh, a);
            acc1[th] = a;
        }
        float hv[32];
        #pragma unroll
        for (int th = 0; th < 8; th++) {
            #pragma unroll
            for (int r = 0; r < 4; r++) hv[4 * th + r] = fast_tanh(acc1[th][r]);
        }
        f32x4 acc2[2];
        acc2[0] = (f32x4){vb2v[0], vb2v[0], vb2v[0], vb2v[0]};
        acc2[1] = (f32x4){vb2v[1], vb2v[1], vb2v[1], vb2v[1]};
        #pragma unroll
        for (int s = 0; s < 4; s++) {
            bf16x8 ah, al;
            #pragma unroll
            for (int i = 0; i < 8; i++) {
                float x = hv[8 * s + i];
                __bf16 h = (__bf16)x; ah[i] = h; al[i] = (__bf16)(x - (float)h);
            }
            #pragma unroll
            for (int nt = 0; nt < 2; nt++) {
                f32x4 a = acc2[nt];
                a = mfma16(ah, w2l[nt * 4 + s], a);
                a = mfma16(al, w2h[nt * 4 + s], a);
                a = mfma16(ah, w2h[nt * 4 + s], a);
                acc2[nt] = a;
            }
        }
        #pragma unroll
        for (int nt = 0; nt < 2; nt++) {
            #pragma unroll
            for (int r = 0; r < 4; r++) {
                int row = rbase + 4 * g + r;
                if (row < B) out[(size_t)row * DD + nt * 16 + m] = acc2[nt][r];
            }
        }
    }
}

// ---- Kernel 2: pair forces + 6 triple grads (MFMA) ------------------------
__global__ __launch_bounds__(256) void k_force(
    const float* __restrict__ z,
    const int*   __restrict__ perm,
    const float* __restrict__ ws,
    const float* __restrict__ pb1,
    const float* __restrict__ pW2,
    float* __restrict__ out,
    float* __restrict__ tripg,
    int np, int nwork)
{
    int lane = threadIdx.x & 63;
    int wid  = blockIdx.x * (blockDim.x >> 6) + (threadIdx.x >> 6);
    int nw   = gridDim.x * (blockDim.x >> 6);
    int g = lane >> 4, m = lane & 15;

    bf16x8 p1h[8], p1l[8], pth[8], ptl[8];
    #pragma unroll
    for (int q = 0; q < 8; q++) {
        p1h[q] = *(const bf16x8*)(ws + WS_FRAG + (size_t)((FP1H + q) * 64 + lane) * 4);
        p1l[q] = *(const bf16x8*)(ws + WS_FRAG + (size_t)((FP1L + q) * 64 + lane) * 4);
        pth[q] = *(const bf16x8*)(ws + WS_FRAG + (size_t)((FPTH + q) * 64 + lane) * 4);
        ptl[q] = *(const bf16x8*)(ws + WS_FRAG + (size_t)((FPTL + q) * 64 + lane) * 4);
    }
    f32x4 pb1f[8];
    #pragma unroll
    for (int th = 0; th < 8; th++)
        pb1f[th] = *(const f32x4*)(pb1 + 16 * th + 4 * g);

    int ntiles = (nwork + 15) >> 4;
    for (int tt = wid; tt < ntiles; tt += nw) {
        int pbase = tt * 16;
        int p = pbase + m;
        int ia = 0, ib = 0;
        if (p < np) {
            i32x2 pr = *(const i32x2*)(perm + 2 * p);
            ia = pr[0]; ib = pr[1];
        } else if (p < nwork) {
            int ti = p - np;
            int i3 = ti >> 1, r3 = ti & 1;
            int j3 = r3 + ((r3 >= i3) ? 1 : 0);
            ia = perm[2 * np + i3];
            ib = perm[2 * np + j3];
        }
        f32x4 xa = *(const f32x4*)(z + (size_t)ia * DD + 8 * g);
        f32x4 xb = *(const f32x4*)(z + (size_t)ia * DD + 8 * g + 4);
        f32x4 ya = *(const f32x4*)(z + (size_t)ib * DD + 8 * g);
        f32x4 yb = *(const f32x4*)(z + (size_t)ib * DD + 8 * g + 4);
        bf16x8 dh, dl;
        #pragma unroll
        for (int i = 0; i < 4; i++) {
            float d = xa[i] - ya[i];
            __bf16 h = (__bf16)d; dh[i] = h; dl[i] = (__bf16)(d - (float)h);
        }
        #pragma unroll
        for (int i = 0; i < 4; i++) {
            float d = xb[i] - yb[i];
            __bf16 h = (__bf16)d; dh[4 + i] = h; dl[4 + i] = (__bf16)(d - (float)h);
        }

        f32x4 acc1[8];
        #pragma unroll
        for (int th = 0; th < 8; th++) {
            f32x4 a = pb1f[th];
            a = mfma16(p1h[th], dl, a);
            a = mfma16(p1l[th], dh, a);
            a = mfma16(p1h[th], dh, a);
            acc1[th] = a;
        }
        float sv[32];
        #pragma unroll
        for (int th = 0; th < 8; th++) {
            f32x4 w2q = *(const f32x4*)(pW2 + 16 * th + 4 * g);
            #pragma unroll
            for (int r = 0; r < 4; r++)
                sv[4 * th + r] = w2q[r] * sech2(acc1[th][r]);
        }
        f32x4 acc2[2];
        acc2[0] = (f32x4){0.f, 0.f, 0.f, 0.f};
        acc2[1] = (f32x4){0.f, 0.f, 0.f, 0.f};
        #pragma unroll
        for (int s = 0; s < 4; s++) {
            bf16x8 ah, al;
            #pragma unroll
            for (int i = 0; i < 8; i++) {
                float x = sv[8 * s + i];
                __bf16 h = (__bf16)x; ah[i] = h; al[i] = (__bf16)(x - (float)h);
            }
            #pragma unroll
            for (int nt = 0; nt < 2; nt++) {
                f32x4 a = acc2[nt];
                a = mfma16(ah, ptl[nt * 4 + s], a);
                a = mfma16(al, pth[nt * 4 + s], a);
                a = mfma16(ah, pth[nt * 4 + s], a);
                acc2[nt] = a;
            }
        }
        // scatter: lane holds g[p2 = pbase+4g+r][j = nt*16+m]
        #pragma unroll
        for (int r = 0; r < 4; r++) {
            int p2 = pbase + 4 * g + r;
            if (p2 < np) {
                i32x2 pr = *(const i32x2*)(perm + 2 * p2);
                #pragma unroll
                for (int nt = 0; nt < 2; nt++) {
                    float v = acc2[nt][r];
                    size_t oa = (size_t)pr[0] * DD + nt * 16 + m;
                    size_t ob = (size_t)pr[1] * DD + nt * 16 + m;
                    out[oa] -= v;
                    out[ob] += v;
                }
            } else if (p2 < nwork) {
                int ti = p2 - np;
                #pragma unroll
                for (int nt = 0; nt < 2; nt++)
                    tripg[ti * DD + nt * 16 + m] = acc2[nt][r];
            }
        }
    }
}

// ---- Kernel 3: deterministic triple combine -------------------------------
__global__ void k_triple_combine(
    const int*   __restrict__ perm,
    const float* __restrict__ tripg,
    float* __restrict__ out,
    int np)
{
    int tid = threadIdx.x;
    if (tid >= 3 * DD) return;
    int i = tid >> 5, d = tid & (DD - 1);
    int row = perm[2 * np + i];
    float s = tripg[(2 * i) * DD + d] + tripg[(2 * i + 1) * DD + d];
    out[(size_t)row * DD + d] -= 2.0f * s;
}

extern "C" void kernel_launch(void* const* d_in, const int* in_sizes, int n_in,
                              void* d_out, int out_size, void* d_ws, size_t ws_size,
                              hipStream_t stream) {
    const float* t    = (const float*)d_in[0];
    const float* z    = (const float*)d_in[1];
    const int*   perm = (const int*)  d_in[2];
    const float* vW1  = (const float*)d_in[3];
    const float* vb1  = (const float*)d_in[4];
    const float* vW2  = (const float*)d_in[5];
    const float* vb2  = (const float*)d_in[6];
    const float* pW1  = (const float*)d_in[7];
    const float* pb1  = (const float*)d_in[8];
    const float* pW2  = (const float*)d_in[9];
    // d_in[10] = pb2: constant, vanishes under grad — unused.

    float* out = (float*)d_out;
    float* ws  = (float*)d_ws;

    int B = in_sizes[2];
    int np, ntr;
    if ((B & 1) == 0) { np = B / 2;       ntr = 0; }
    else              { np = (B - 3) / 2; ntr = 1; }

    k_prep<<<17, 256, 0, stream>>>(t, vW1, vb1, vW2, pW1, ws);

    k_dzdt<<<512, 256, 0, stream>>>(z, ws, vb2, out, B);

    int nwork = np + (ntr ? 6 : 0);
    if (nwork > 0) {
        k_force<<<512, 256, 0, stream>>>(z, perm, ws, pb1, pW2, out,
                                         ws + WS_TRIPG, np, nwork);
    }
    if (ntr) {
        k_triple_combine<<<1, 128, 0, stream>>>(perm, ws + WS_TRIPG, out, np);
    }
}